// Round 10
// baseline (627.274 us; speedup 1.0000x reference)
//
#include <hip/hip_runtime.h>
#include <hip/hip_bf16.h>
#include <math.h>

#define EMBED 1024
#define FFN   4096
#define NW    8
#define MTOT  32768   // 16*2048

#define BM 128
#define BN 128
#define BK 64
#define NT (FFN / BK)   // 64 K-tiles

#define STRIP 128
#define KPT   8

typedef __attribute__((ext_vector_type(8))) short          short8v;
typedef __attribute__((ext_vector_type(8))) unsigned short ushort8v;
typedef __attribute__((ext_vector_type(4))) float          f32x4;

typedef __attribute__((address_space(1))) void gvoid_t;
typedef __attribute__((address_space(3))) void svoid_t;

static __device__ __forceinline__ unsigned short bf16bits(float f) {
    __hip_bfloat16 h = __float2bfloat16(f);
    return *reinterpret_cast<unsigned short*>(&h);
}

// ---------------- W2 f32 -> bf16 (once, into ws) ----------------
__global__ __launch_bounds__(256) void cvtW2_kernel(const float* __restrict__ W2,
                                                    __hip_bfloat16* __restrict__ Bw) {
    const long i0 = ((long)blockIdx.x * 256 + threadIdx.x) * 8;
    const float4 a = *(const float4*)(W2 + i0);
    const float4 b = *(const float4*)(W2 + i0 + 4);
    float fs[8] = {a.x, a.y, a.z, a.w, b.x, b.y, b.z, b.w};
    ushort8v v;
#pragma unroll
    for (int t = 0; t < 8; ++t) v[t] = bf16bits(fs[t]);
    *reinterpret_cast<ushort8v*>(Bw + i0) = v;
}

// ---------------- producer: h[m,k] = relu(b1[k] + qz[m,:]·W1[k,:]) ----------------
__global__ __launch_bounds__(256) void hprod2_kernel(
    const float* __restrict__ x, const float* __restrict__ theta,
    const float* __restrict__ W1, const float* __restrict__ b1,
    __hip_bfloat16* __restrict__ h, int m0)
{
    __shared__ float qz_lds[STRIP][NW];
    const int tid   = threadIdx.x;
    const int khalf = blockIdx.x & 1;
    const int strip = blockIdx.x >> 1;
    const int k0    = khalf * 2048 + tid * KPT;

    float w1r[KPT][NW];
    float b1r[KPT];
#pragma unroll
    for (int i = 0; i < KPT; ++i) {
        const float4 a = *(const float4*)(W1 + (long)(k0 + i) * NW);
        const float4 b = *(const float4*)(W1 + (long)(k0 + i) * NW + 4);
        w1r[i][0] = a.x; w1r[i][1] = a.y; w1r[i][2] = a.z; w1r[i][3] = a.w;
        w1r[i][4] = b.x; w1r[i][5] = b.y; w1r[i][6] = b.z; w1r[i][7] = b.w;
        b1r[i] = b1[k0 + i];
    }

    if (tid < STRIP) {
        const long m = (long)m0 + (long)strip * STRIP + tid;
        const float* xr = x + m * (long)EMBED;
#pragma unroll
        for (int w = 0; w < NW; ++w)
            qz_lds[tid][w] = cosf(xr[w]) * cosf(theta[w]);
    }
    __syncthreads();

    __hip_bfloat16* hp = h + ((long)strip * STRIP) * FFN + k0;
    for (int r = 0; r < STRIP; ++r) {
        float q[NW];
#pragma unroll
        for (int w = 0; w < NW; ++w) q[w] = qz_lds[r][w];
        ushort8v hv;
#pragma unroll
        for (int i = 0; i < KPT; ++i) {
            float acc = b1r[i];
#pragma unroll
            for (int w = 0; w < NW; ++w) acc = fmaf(q[w], w1r[i][w], acc);
            hv[i] = bf16bits(fmaxf(acc, 0.0f));
        }
        *reinterpret_cast<ushort8v*>(hp + (long)r * FFN) = hv;
    }
}

// ---------------- GEMM v10: R9 + B direct-to-registers (no B LDS) ----------------
// out[M,1024] = h[M,4096] @ W2bf[1024,4096]^T + b2
// R9 measured: occupancy-overlap (2.4 blk/CU) beats every phase schedule;
// limiters now VALUBusy 41% (staging addr) + LDS port alternation.
// W2 is 8.4MB, L2/L3-hot, reused by every block => skip LDS for B entirely:
// per tile each wave loads its 8 B-frags (dwordx4, 16 rows x 64B fully-used
// lines) straight to VGPRs. LDS/block 32->16KB, LDS traffic halves, DMA
// issue halves -> ~5 blocks/CU co-resident (vs 2.4) hide drains (m114).
// A path unchanged: gload_lds DMA + proven zero-conflict swizzle pair.
// Plain __syncthreads structure (R9-proven); pn-fastest XCD map.
__global__ __launch_bounds__(256) void gemm10_kernel(
    const __hip_bfloat16* __restrict__ A,   // [rows][FFN] chunk-local h
    const __hip_bfloat16* __restrict__ Bw,  // [EMBED][FFN] W2 bf16
    const float* __restrict__ b2,
    float* __restrict__ out, long m0, int nPm)
{
    __shared__ __align__(16) __hip_bfloat16 As[BM * BK];  // 16 KB (A only)

    const int tid = threadIdx.x, wid = tid >> 6, lane = tid & 63;
    const int l15 = lane & 15, l4 = lane >> 4;
    const int wr = wid >> 1, wc = wid & 1;          // 2M x 2N wave grid

    // XCD map: bid = xcd + 8*j; per pm, 8 pn back-to-back on one XCD.
    const int xcd = blockIdx.x & 7, j = blockIdx.x >> 3;
    const int pn  = j & 7;
    const int pm  = xcd * (nPm >> 3) + (j >> 3);

    // A staging: 8 threads/row (8x16B=128B row); 4 sweeps of 32 rows.
    // Global source col pre-XORed by row&7 -> linear LDS + XOR'd read, 0 conf.
    const int srow  = tid >> 3;                     // 0..31
    const int colsw = ((tid & 7) ^ (srow & 7)) * 8;
    const __hip_bfloat16* Ag = A + (long)(pm * BM + srow) * FFN + colsw;

    // B direct: per (ni) row base, col l4*8; per tile add t*BK (+ kk*32)
    const __hip_bfloat16* Bbase[4];
#pragma unroll
    for (int ni = 0; ni < 4; ++ni)
        Bbase[ni] = Bw + (long)(pn * BN + wc * 64 + ni * 16 + l15) * FFN + l4 * 8;

    f32x4 acc[4][4];
#pragma unroll
    for (int i = 0; i < 4; ++i)
#pragma unroll
        for (int jj = 0; jj < 4; ++jj) acc[i][jj] = (f32x4){0.f, 0.f, 0.f, 0.f};

    const int rx = (l15 & 7) << 3;   // A read-side elem XOR; row&7 == l15&7

    for (int t = 0; t < NT; ++t) {
        __syncthreads();   // previous tile's A-reads complete before overwrite
#pragma unroll
        for (int s = 0; s < 4; ++s)
            __builtin_amdgcn_global_load_lds(
                (gvoid_t*)(Ag + (long)(s * 32) * FFN + t * BK),
                (svoid_t*)(&As[(s * 32 + wid * 8) * BK]), 16, 0, 0);

        // B frags: 8 dwordx4/wave from L2/L3 (issued early; compiler-managed
        // waitcnt covers the reg dependency; __syncthreads drain covers A DMA)
        short8v bv[4][2];
#pragma unroll
        for (int ni = 0; ni < 4; ++ni)
#pragma unroll
            for (int kk = 0; kk < 2; ++kk)
                bv[ni][kk] = *reinterpret_cast<const short8v*>(
                    Bbase[ni] + t * BK + kk * 32);

        __syncthreads();   // A tile resident

        short8v av[4][2];
#pragma unroll
        for (int mi = 0; mi < 4; ++mi)
#pragma unroll
            for (int kk = 0; kk < 2; ++kk) {
                const int row = wr * 64 + mi * 16 + l15;
                av[mi][kk] = *reinterpret_cast<const short8v*>(
                    &As[row * BK + ((kk * 32 + l4 * 8) ^ rx)]);
            }
#pragma unroll
        for (int mi = 0; mi < 4; ++mi)
#pragma unroll
            for (int ni = 0; ni < 4; ++ni)
#pragma unroll
                for (int kk = 0; kk < 2; ++kk)
                    acc[mi][ni] = __builtin_amdgcn_mfma_f32_16x16x32_bf16(
                        av[mi][kk], bv[ni][kk], acc[mi][ni], 0, 0, 0);
    }

    // epilogue: + b2, f32 store. C/D: col=lane&15, row=(lane>>4)*4+reg
    const int gn0 = pn * BN + wc * 64;
    float bias[4];
#pragma unroll
    for (int ni = 0; ni < 4; ++ni) bias[ni] = b2[gn0 + ni * 16 + l15];
    const long gm0 = m0 + (long)pm * BM + wr * 64;
#pragma unroll
    for (int mi = 0; mi < 4; ++mi)
#pragma unroll
        for (int ni = 0; ni < 4; ++ni)
#pragma unroll
            for (int jj = 0; jj < 4; ++jj) {
                const long row = gm0 + mi * 16 + l4 * 4 + jj;
                out[row * EMBED + gn0 + ni * 16 + l15] = acc[mi][ni][jj] + bias[ni];
            }
}

extern "C" void kernel_launch(void* const* d_in, const int* in_sizes, int n_in,
                              void* d_out, int out_size, void* d_ws, size_t ws_size,
                              hipStream_t stream)
{
    const float* x     = (const float*)d_in[0];
    const float* theta = (const float*)d_in[1];
    const float* W1    = (const float*)d_in[2];
    const float* b1    = (const float*)d_in[3];
    const float* W2    = (const float*)d_in[4];
    const float* b2    = (const float*)d_in[5];
    float* out = (float*)d_out;

    const size_t w2b = (size_t)EMBED * FFN * 2;          // 8.4 MB bf16 W2
    __hip_bfloat16* Bw = (__hip_bfloat16*)d_ws;
    __hip_bfloat16* h  = (__hip_bfloat16*)((char*)d_ws + w2b);
    const size_t avail = ws_size > w2b ? ws_size - w2b : 0;

    long chunk = (long)((avail / ((size_t)FFN * 2)) & ~2047UL); // mult of 2048 rows
    if (chunk > MTOT) chunk = MTOT;
    if (chunk < 2048) chunk = 2048;

    cvtW2_kernel<<<(EMBED * FFN) / 2048, 256, 0, stream>>>(W2, Bw);

    for (long m0 = 0; m0 < MTOT; m0 += chunk) {
        const long rows = (MTOT - m0 < chunk) ? (MTOT - m0) : chunk;
        hprod2_kernel<<<(int)((rows / STRIP) * 2), 256, 0, stream>>>(
            x, theta, W1, b1, h, (int)m0);
        const int nPm = (int)(rows / BM);                 // multiple of 16
        gemm10_kernel<<<nPm * 8, 256, 0, stream>>>(h, Bw, b2, out, m0, nPm);
    }
}

// Round 11
// 563.644 us; speedup vs baseline: 1.1129x; 1.1129x over previous
//
#include <hip/hip_runtime.h>
#include <hip/hip_bf16.h>
#include <math.h>

#define EMBED 1024
#define FFN   4096
#define NW    8
#define MTOT  32768   // 16*2048

#define BM 256
#define BN 128
#define BK 64
#define NT (FFN / BK)   // 64 K-tiles

#define STRIP 128
#define KPT   8

typedef __attribute__((ext_vector_type(8))) short          short8v;
typedef __attribute__((ext_vector_type(8))) unsigned short ushort8v;
typedef __attribute__((ext_vector_type(4))) float          f32x4;

typedef __attribute__((address_space(1))) void gvoid_t;
typedef __attribute__((address_space(3))) void svoid_t;

static __device__ __forceinline__ unsigned short bf16bits(float f) {
    __hip_bfloat16 h = __float2bfloat16(f);
    return *reinterpret_cast<unsigned short*>(&h);
}

// ---------------- W2 f32 -> bf16 (once, into ws) ----------------
__global__ __launch_bounds__(256) void cvtW2_kernel(const float* __restrict__ W2,
                                                    __hip_bfloat16* __restrict__ Bw) {
    const long i0 = ((long)blockIdx.x * 256 + threadIdx.x) * 8;
    const float4 a = *(const float4*)(W2 + i0);
    const float4 b = *(const float4*)(W2 + i0 + 4);
    float fs[8] = {a.x, a.y, a.z, a.w, b.x, b.y, b.z, b.w};
    ushort8v v;
#pragma unroll
    for (int t = 0; t < 8; ++t) v[t] = bf16bits(fs[t]);
    *reinterpret_cast<ushort8v*>(Bw + i0) = v;
}

// ---------------- producer: h[m,k] = relu(b1[k] + qz[m,:]·W1[k,:]) ----------------
__global__ __launch_bounds__(256) void hprod2_kernel(
    const float* __restrict__ x, const float* __restrict__ theta,
    const float* __restrict__ W1, const float* __restrict__ b1,
    __hip_bfloat16* __restrict__ h, int m0)
{
    __shared__ float qz_lds[STRIP][NW];
    const int tid   = threadIdx.x;
    const int khalf = blockIdx.x & 1;
    const int strip = blockIdx.x >> 1;
    const int k0    = khalf * 2048 + tid * KPT;

    float w1r[KPT][NW];
    float b1r[KPT];
#pragma unroll
    for (int i = 0; i < KPT; ++i) {
        const float4 a = *(const float4*)(W1 + (long)(k0 + i) * NW);
        const float4 b = *(const float4*)(W1 + (long)(k0 + i) * NW + 4);
        w1r[i][0] = a.x; w1r[i][1] = a.y; w1r[i][2] = a.z; w1r[i][3] = a.w;
        w1r[i][4] = b.x; w1r[i][5] = b.y; w1r[i][6] = b.z; w1r[i][7] = b.w;
        b1r[i] = b1[k0 + i];
    }

    if (tid < STRIP) {
        const long m = (long)m0 + (long)strip * STRIP + tid;
        const float* xr = x + m * (long)EMBED;
#pragma unroll
        for (int w = 0; w < NW; ++w)
            qz_lds[tid][w] = cosf(xr[w]) * cosf(theta[w]);
    }
    __syncthreads();

    __hip_bfloat16* hp = h + ((long)strip * STRIP) * FFN + k0;
    for (int r = 0; r < STRIP; ++r) {
        float q[NW];
#pragma unroll
        for (int w = 0; w < NW; ++w) q[w] = qz_lds[r][w];
        ushort8v hv;
#pragma unroll
        for (int i = 0; i < KPT; ++i) {
            float acc = b1r[i];
#pragma unroll
            for (int w = 0; w < NW; ++w) acc = fmaf(q[w], w1r[i][w], acc);
            hv[i] = bf16bits(fmaxf(acc, 0.0f));
        }
        *reinterpret_cast<ushort8v*>(hp + (long)r * FFN) = hv;
    }
}

// ---------------- GEMM v11: R9 structure, MFMA-bound re-blocking ----------------
// out[M,1024] = h[M,4096] @ W2bf[1024,4096]^T + b2
// R9 accounting: mi=ni=4 blocking is LDS-port-heavy (per tile per block:
// port 770 cyc > MFMA 621) -> port is the wall. Fix = m201's wave tile
// WITHOUT its lockstep schedule: mi=8, ni=4 => per-thread reads 24 b128
// (port 1152) vs 256 MFMA (1242 cyc) -> MFMA-bound. Keep R9's proven
// simple structure: single-buffer LDS, 2x __syncthreads, gload_lds DMA,
// zero-conflict swizzle pair, pn-fastest XCD map; rely on 2 independent
// blocks/CU to overlap port/MFMA/drains (m114).
// BM=256 BN=128, 4 waves (2Mx2N), wave owns 128x64. LDS 48KB. acc 8x4.
__global__ __launch_bounds__(256) void gemm11_kernel(
    const __hip_bfloat16* __restrict__ A,   // [rows][FFN] chunk-local h
    const __hip_bfloat16* __restrict__ Bw,  // [EMBED][FFN] W2 bf16
    const float* __restrict__ b2,
    float* __restrict__ out, long m0, int nPm)
{
    __shared__ __align__(16) __hip_bfloat16 As[BM * BK];  // 32 KB
    __shared__ __align__(16) __hip_bfloat16 Bs[BN * BK];  // 16 KB

    const int tid = threadIdx.x, wid = tid >> 6, lane = tid & 63;
    const int l15 = lane & 15, l4 = lane >> 4;
    const int wr = wid >> 1, wc = wid & 1;          // 2M x 2N wave grid

    // XCD map: bid = xcd + 8*j; per pm, 8 pn back-to-back on one XCD
    // -> A panel (2MB) L2-hot across 8 consecutive blocks.
    const int xcd = blockIdx.x & 7, j = blockIdx.x >> 3;
    const int pn  = j & 7;
    const int pm  = xcd * (nPm >> 3) + (j >> 3);

    // staging: 8 threads/row (8x16B=128B row); sweeps of 32 rows.
    // Global source col pre-XORed by row&7 -> linear LDS + XOR'd read, 0 conf.
    const int srow  = tid >> 3;                     // 0..31
    const int colsw = ((tid & 7) ^ (srow & 7)) * 8;

    const __hip_bfloat16* Ag = A  + (long)(pm * BM + srow) * FFN + colsw;
    const __hip_bfloat16* Bg = Bw + (long)(pn * BN + srow) * FFN + colsw;

    f32x4 acc[8][4];
#pragma unroll
    for (int i = 0; i < 8; ++i)
#pragma unroll
        for (int jj = 0; jj < 4; ++jj) acc[i][jj] = (f32x4){0.f, 0.f, 0.f, 0.f};

    const int rx = (l15 & 7) << 3;   // read-side elem XOR; row&7 == l15&7

    for (int t = 0; t < NT; ++t) {
        __syncthreads();   // previous tile's reads complete before overwrite
        // stage A: 8 sweeps of 32 rows; B: 4 sweeps
#pragma unroll
        for (int s = 0; s < 8; ++s)
            __builtin_amdgcn_global_load_lds(
                (gvoid_t*)(Ag + (long)(s * 32) * FFN + t * BK),
                (svoid_t*)(&As[(s * 32 + wid * 8) * BK]), 16, 0, 0);
#pragma unroll
        for (int s = 0; s < 4; ++s)
            __builtin_amdgcn_global_load_lds(
                (gvoid_t*)(Bg + (long)(s * 32) * FFN + t * BK),
                (svoid_t*)(&Bs[(s * 32 + wid * 8) * BK]), 16, 0, 0);
        __syncthreads();   // tile resident (vmcnt0 drain; other block hides)

        // compute: kk-major so bv is read once per kk and reused by 8 mi
#pragma unroll
        for (int kk = 0; kk < 2; ++kk) {
            short8v bv[4];
#pragma unroll
            for (int ni = 0; ni < 4; ++ni) {
                const int row = wc * 64 + ni * 16 + l15;
                bv[ni] = *reinterpret_cast<const short8v*>(
                    &Bs[row * BK + ((kk * 32 + l4 * 8) ^ rx)]);
            }
#pragma unroll
            for (int mi = 0; mi < 8; ++mi) {
                const int row = wr * 128 + mi * 16 + l15;
                const short8v av = *reinterpret_cast<const short8v*>(
                    &As[row * BK + ((kk * 32 + l4 * 8) ^ rx)]);
#pragma unroll
                for (int ni = 0; ni < 4; ++ni)
                    acc[mi][ni] = __builtin_amdgcn_mfma_f32_16x16x32_bf16(
                        av, bv[ni], acc[mi][ni], 0, 0, 0);
            }
        }
    }

    // epilogue: + b2, f32 store. C/D: col=lane&15, row=(lane>>4)*4+reg
    const int gn0 = pn * BN + wc * 64;
    float bias[4];
#pragma unroll
    for (int ni = 0; ni < 4; ++ni) bias[ni] = b2[gn0 + ni * 16 + l15];
    const long gm0 = m0 + (long)pm * BM + wr * 128;
#pragma unroll
    for (int mi = 0; mi < 8; ++mi)
#pragma unroll
        for (int ni = 0; ni < 4; ++ni)
#pragma unroll
            for (int jj = 0; jj < 4; ++jj) {
                const long row = gm0 + mi * 16 + l4 * 4 + jj;
                out[row * EMBED + gn0 + ni * 16 + l15] = acc[mi][ni][jj] + bias[ni];
            }
}

extern "C" void kernel_launch(void* const* d_in, const int* in_sizes, int n_in,
                              void* d_out, int out_size, void* d_ws, size_t ws_size,
                              hipStream_t stream)
{
    const float* x     = (const float*)d_in[0];
    const float* theta = (const float*)d_in[1];
    const float* W1    = (const float*)d_in[2];
    const float* b1    = (const float*)d_in[3];
    const float* W2    = (const float*)d_in[4];
    const float* b2    = (const float*)d_in[5];
    float* out = (float*)d_out;

    const size_t w2b = (size_t)EMBED * FFN * 2;          // 8.4 MB bf16 W2
    __hip_bfloat16* Bw = (__hip_bfloat16*)d_ws;
    __hip_bfloat16* h  = (__hip_bfloat16*)((char*)d_ws + w2b);
    const size_t avail = ws_size > w2b ? ws_size - w2b : 0;

    long chunk = (long)((avail / ((size_t)FFN * 2)) & ~2047UL); // mult of 2048 rows
    if (chunk > MTOT) chunk = MTOT;
    if (chunk < 2048) chunk = 2048;

    cvtW2_kernel<<<(EMBED * FFN) / 2048, 256, 0, stream>>>(W2, Bw);

    for (long m0 = 0; m0 < MTOT; m0 += chunk) {
        const long rows = (MTOT - m0 < chunk) ? (MTOT - m0) : chunk;
        hprod2_kernel<<<(int)((rows / STRIP) * 2), 256, 0, stream>>>(
            x, theta, W1, b1, h, (int)m0);
        const int nPm = (int)(rows / BM);                 // multiple of 8
        gemm11_kernel<<<nPm * 8, 256, 0, stream>>>(h, Bw, b2, out, m0, nPm);
    }
}

// Round 12
// 360.740 us; speedup vs baseline: 1.7389x; 1.5625x over previous
//
#include <hip/hip_runtime.h>
#include <hip/hip_bf16.h>
#include <math.h>

#define EMBED 1024
#define FFN   4096
#define NW    8
#define MTOT  32768   // 16*2048

#define BM 128
#define BN 128
#define BK 64
#define NT (FFN / BK)   // 64 K-tiles

#define STRIP 128
#define KPT   8

typedef __attribute__((ext_vector_type(8))) short          short8v;
typedef __attribute__((ext_vector_type(8))) unsigned short ushort8v;
typedef __attribute__((ext_vector_type(4))) float          f32x4;

typedef __attribute__((address_space(1))) void gvoid_t;
typedef __attribute__((address_space(3))) void svoid_t;

static __device__ __forceinline__ unsigned short bf16bits(float f) {
    __hip_bfloat16 h = __float2bfloat16(f);
    return *reinterpret_cast<unsigned short*>(&h);
}

// ---------------- W2 f32 -> bf16 (once, into ws) ----------------
__global__ __launch_bounds__(256) void cvtW2_kernel(const float* __restrict__ W2,
                                                    __hip_bfloat16* __restrict__ Bw) {
    const long i0 = ((long)blockIdx.x * 256 + threadIdx.x) * 8;
    const float4 a = *(const float4*)(W2 + i0);
    const float4 b = *(const float4*)(W2 + i0 + 4);
    float fs[8] = {a.x, a.y, a.z, a.w, b.x, b.y, b.z, b.w};
    ushort8v v;
#pragma unroll
    for (int t = 0; t < 8; ++t) v[t] = bf16bits(fs[t]);
    *reinterpret_cast<ushort8v*>(Bw + i0) = v;
}

// ---------------- producer: h[m,k] = relu(b1[k] + qz[m,:]·W1[k,:]) ----------------
__global__ __launch_bounds__(256) void hprod2_kernel(
    const float* __restrict__ x, const float* __restrict__ theta,
    const float* __restrict__ W1, const float* __restrict__ b1,
    __hip_bfloat16* __restrict__ h, int m0)
{
    __shared__ float qz_lds[STRIP][NW];
    const int tid   = threadIdx.x;
    const int khalf = blockIdx.x & 1;
    const int strip = blockIdx.x >> 1;
    const int k0    = khalf * 2048 + tid * KPT;

    float w1r[KPT][NW];
    float b1r[KPT];
#pragma unroll
    for (int i = 0; i < KPT; ++i) {
        const float4 a = *(const float4*)(W1 + (long)(k0 + i) * NW);
        const float4 b = *(const float4*)(W1 + (long)(k0 + i) * NW + 4);
        w1r[i][0] = a.x; w1r[i][1] = a.y; w1r[i][2] = a.z; w1r[i][3] = a.w;
        w1r[i][4] = b.x; w1r[i][5] = b.y; w1r[i][6] = b.z; w1r[i][7] = b.w;
        b1r[i] = b1[k0 + i];
    }

    if (tid < STRIP) {
        const long m = (long)m0 + (long)strip * STRIP + tid;
        const float* xr = x + m * (long)EMBED;
#pragma unroll
        for (int w = 0; w < NW; ++w)
            qz_lds[tid][w] = cosf(xr[w]) * cosf(theta[w]);
    }
    __syncthreads();

    __hip_bfloat16* hp = h + ((long)strip * STRIP) * FFN + k0;
    for (int r = 0; r < STRIP; ++r) {
        float q[NW];
#pragma unroll
        for (int w = 0; w < NW; ++w) q[w] = qz_lds[r][w];
        ushort8v hv;
#pragma unroll
        for (int i = 0; i < KPT; ++i) {
            float acc = b1r[i];
#pragma unroll
            for (int w = 0; w < NW; ++w) acc = fmaf(q[w], w1r[i][w], acc);
            hv[i] = bf16bits(fmaxf(acc, 0.0f));
        }
        *reinterpret_cast<ushort8v*>(hp + (long)r * FFN) = hv;
    }
}

// ---------------- GEMM v12: R9 under the 128-reg occupancy cliff ----------------
// out[M,1024] = h[M,4096] @ W2bf[1024,4096]^T + b2
// R11 lesson (m69 ladder, unified VGPR+AGPR file): waves/CU halve at total
// regs 64/128/256. R9 = 76+64 = 140 regs -> capped 8 waves/CU (2 blocks).
// R11 = 284 -> 4 waves/CU (1 block) -> 550us. Perf tracks co-resident blocks.
// v12 = R9 exactly, but (1) kk-major compute so only ~20 frag regs live
// (was 64), (2) __launch_bounds__(256,4) => 4 waves/EU = 16 waves/CU target,
// forcing total <=128 -> 4 independent blocks/CU (LDS 32KB allows 5).
__global__ __launch_bounds__(256, 4) void gemm12_kernel(
    const __hip_bfloat16* __restrict__ A,   // [rows][FFN] chunk-local h
    const __hip_bfloat16* __restrict__ Bw,  // [EMBED][FFN] W2 bf16
    const float* __restrict__ b2,
    float* __restrict__ out, long m0, int nPm)
{
    __shared__ __align__(16) __hip_bfloat16 As[BM * BK];  // 16 KB
    __shared__ __align__(16) __hip_bfloat16 Bs[BN * BK];  // 16 KB

    const int tid = threadIdx.x, wid = tid >> 6, lane = tid & 63;
    const int l15 = lane & 15, l4 = lane >> 4;
    const int wr = wid >> 1, wc = wid & 1;          // 2M x 2N wave grid

    // XCD map: bid = xcd + 8*j; per pm, 8 pn back-to-back on one XCD.
    const int xcd = blockIdx.x & 7, j = blockIdx.x >> 3;
    const int pn  = j & 7;
    const int pm  = xcd * (nPm >> 3) + (j >> 3);

    // staging: 8 threads/row (8x16B=128B row); 4 sweeps of 32 rows.
    // Global source col pre-XORed by row&7 -> linear LDS + XOR'd read, 0 conf.
    const int srow  = tid >> 3;                     // 0..31
    const int colsw = ((tid & 7) ^ (srow & 7)) * 8;

    const __hip_bfloat16* Ag = A  + (long)(pm * BM + srow) * FFN + colsw;
    const __hip_bfloat16* Bg = Bw + (long)(pn * BN + srow) * FFN + colsw;

    f32x4 acc[4][4];
#pragma unroll
    for (int i = 0; i < 4; ++i)
#pragma unroll
        for (int jj = 0; jj < 4; ++jj) acc[i][jj] = (f32x4){0.f, 0.f, 0.f, 0.f};

    const int rx = (l15 & 7) << 3;   // read-side elem XOR; row&7 == l15&7

    for (int t = 0; t < NT; ++t) {
        __syncthreads();   // previous tile's reads complete before overwrite
#pragma unroll
        for (int s = 0; s < 4; ++s) {
            __builtin_amdgcn_global_load_lds(
                (gvoid_t*)(Ag + (long)(s * 32) * FFN + t * BK),
                (svoid_t*)(&As[(s * 32 + wid * 8) * BK]), 16, 0, 0);
            __builtin_amdgcn_global_load_lds(
                (gvoid_t*)(Bg + (long)(s * 32) * FFN + t * BK),
                (svoid_t*)(&Bs[(s * 32 + wid * 8) * BK]), 16, 0, 0);
        }
        __syncthreads();   // tile resident (vmcnt0 drain; sibling blocks hide)

        // kk-major: narrow liveness (bv[4]=16 + av=4 regs live, not 64)
#pragma unroll
        for (int kk = 0; kk < 2; ++kk) {
            short8v bv[4];
#pragma unroll
            for (int ni = 0; ni < 4; ++ni) {
                const int row = wc * 64 + ni * 16 + l15;
                bv[ni] = *reinterpret_cast<const short8v*>(
                    &Bs[row * BK + ((kk * 32 + l4 * 8) ^ rx)]);
            }
#pragma unroll
            for (int mi = 0; mi < 4; ++mi) {
                const int row = wr * 64 + mi * 16 + l15;
                const short8v av = *reinterpret_cast<const short8v*>(
                    &As[row * BK + ((kk * 32 + l4 * 8) ^ rx)]);
#pragma unroll
                for (int ni = 0; ni < 4; ++ni)
                    acc[mi][ni] = __builtin_amdgcn_mfma_f32_16x16x32_bf16(
                        av, bv[ni], acc[mi][ni], 0, 0, 0);
            }
        }
    }

    // epilogue: + b2, f32 store. C/D: col=lane&15, row=(lane>>4)*4+reg
    const int gn0 = pn * BN + wc * 64;
    float bias[4];
#pragma unroll
    for (int ni = 0; ni < 4; ++ni) bias[ni] = b2[gn0 + ni * 16 + l15];
    const long gm0 = m0 + (long)pm * BM + wr * 64;
#pragma unroll
    for (int mi = 0; mi < 4; ++mi)
#pragma unroll
        for (int ni = 0; ni < 4; ++ni)
#pragma unroll
            for (int jj = 0; jj < 4; ++jj) {
                const long row = gm0 + mi * 16 + l4 * 4 + jj;
                out[row * EMBED + gn0 + ni * 16 + l15] = acc[mi][ni][jj] + bias[ni];
            }
}

extern "C" void kernel_launch(void* const* d_in, const int* in_sizes, int n_in,
                              void* d_out, int out_size, void* d_ws, size_t ws_size,
                              hipStream_t stream)
{
    const float* x     = (const float*)d_in[0];
    const float* theta = (const float*)d_in[1];
    const float* W1    = (const float*)d_in[2];
    const float* b1    = (const float*)d_in[3];
    const float* W2    = (const float*)d_in[4];
    const float* b2    = (const float*)d_in[5];
    float* out = (float*)d_out;

    const size_t w2b = (size_t)EMBED * FFN * 2;          // 8.4 MB bf16 W2
    __hip_bfloat16* Bw = (__hip_bfloat16*)d_ws;
    __hip_bfloat16* h  = (__hip_bfloat16*)((char*)d_ws + w2b);
    const size_t avail = ws_size > w2b ? ws_size - w2b : 0;

    long chunk = (long)((avail / ((size_t)FFN * 2)) & ~2047UL); // mult of 2048 rows
    if (chunk > MTOT) chunk = MTOT;
    if (chunk < 2048) chunk = 2048;

    cvtW2_kernel<<<(EMBED * FFN) / 2048, 256, 0, stream>>>(W2, Bw);

    for (long m0 = 0; m0 < MTOT; m0 += chunk) {
        const long rows = (MTOT - m0 < chunk) ? (MTOT - m0) : chunk;
        hprod2_kernel<<<(int)((rows / STRIP) * 2), 256, 0, stream>>>(
            x, theta, W1, b1, h, (int)m0);
        const int nPm = (int)(rows / BM);                 // multiple of 16
        gemm12_kernel<<<nPm * 8, 256, 0, stream>>>(h, Bw, b2, out, m0, nPm);
    }
}